// Round 4
// baseline (192.870 us; speedup 1.0000x reference)
//
#include <hip/hip_runtime.h>
#include <hip/hip_bf16.h>
#include <cstdint>

#define IDIM 1024
#define HID  256

typedef __attribute__((ext_vector_type(4))) float f32x4;
typedef __attribute__((ext_vector_type(8))) short short8;
typedef __attribute__((ext_vector_type(4))) unsigned int u32x4;

__device__ __forceinline__ unsigned pk_bf16(float a, float b) {
  __hip_bfloat162 h = __float22bfloat162_rn(make_float2(a, b));
  unsigned r; __builtin_memcpy(&r, &h, 4); return r;
}

// ---------------------------------------------------------------------------
// Prep: W1bT[n][k] = bf16(ln_w[k] * W1[k][n]); t2[n]=sum ln_w*W1; tc1=sum ln_b*W1+b1
// ---------------------------------------------------------------------------
__global__ __launch_bounds__(256)
void prep_kernel(const float* __restrict__ W1, const float* __restrict__ lnw,
                 const float* __restrict__ lnb, const float* __restrict__ b1,
                 unsigned short* __restrict__ w1bt, float* __restrict__ t2g,
                 float* __restrict__ tc1g) {
  const int t  = threadIdx.x;
  const int ni = t & 3, kg = t >> 2;
  const int n  = blockIdx.x * 4 + ni;
  const int k0 = kg * 16;
  float s1 = 0.f, s2 = 0.f;
  unsigned pk[8];
#pragma unroll
  for (int j = 0; j < 16; j += 2) {
    const int k = k0 + j;
    const float v0 = W1[(size_t)k * HID + n];
    const float v1 = W1[(size_t)(k + 1) * HID + n];
    const float sc0 = lnw[k] * v0, sc1 = lnw[k + 1] * v1;
    s2 += sc0 + sc1;
    s1 = fmaf(lnb[k], v0, fmaf(lnb[k + 1], v1, s1));
    pk[j >> 1] = pk_bf16(sc0, sc1);
  }
  u32x4* dst = reinterpret_cast<u32x4*>(w1bt + (size_t)n * IDIM + k0);
  dst[0] = u32x4{pk[0], pk[1], pk[2], pk[3]};
  dst[1] = u32x4{pk[4], pk[5], pk[6], pk[7]};
  __shared__ float red[2][64][4];
  red[0][kg][ni] = s1; red[1][kg][ni] = s2;
  __syncthreads();
  if (t < 4) {
    float a = 0.f, b = 0.f;
    for (int i = 0; i < 64; ++i) { a += red[0][i][t]; b += red[1][i][t]; }
    const int nn = blockIdx.x * 4 + t;
    tc1g[nn] = a + b1[nn];
    t2g[nn]  = b;
  }
}

// ---------------------------------------------------------------------------
// Head: barrier-free register-pipelined main loop.
// Block = 64 rows x 256 cols, 4 waves; wave w: all 64 rows x cols [w*64,+64).
// Per BK=32 step, each lane loads its MFMA fragments DIRECTLY from global:
//   A: 4 m-frags x 8 fp32 (2x dwordx4) from emb row (m0+mi*16+lr), k=lk*8..+8
//   B: 4 n-frags x 8 bf16 (1x dwordx4) from w1bt row (w*64+ni*16+lr)  [L2-res]
// 2-deep named register pipeline (A0/B0, A1/B1); compiler emits counted
// vmcnt waits. Stats accumulated from the fp32 A regs before bf16 pack.
// A is read by all 4 waves (dups hit L1/L2, same CU); HBM sees it once.
// No LDS in the loop; LDS only for per-wave stats + partial-out reduce.
// ---------------------------------------------------------------------------
__global__ __launch_bounds__(256, 2)
void head_kernel(const float* __restrict__ emb,
                 const unsigned short* __restrict__ w1bt,
                 const float* __restrict__ t2g, const float* __restrict__ tc1g,
                 const float* __restrict__ w2g, const float* __restrict__ b2g,
                 float* __restrict__ out) {
  __shared__ float statsS[4][128];  // [wave][row*2]: mu*rs, rs
  __shared__ float poutS[4][128];   // [wave][row*2+o]: partial out

  const int t  = threadIdx.x;
  const int l  = t & 63;
  const int w  = t >> 6;
  const int lr = l & 15;
  const int lk = l >> 4;
  const int m0 = blockIdx.x * 64;

  const float* ap[4];
  const unsigned short* bp[4];
#pragma unroll
  for (int mi = 0; mi < 4; ++mi)
    ap[mi] = emb + (size_t)(m0 + mi * 16 + lr) * IDIM + lk * 8;
#pragma unroll
  for (int ni = 0; ni < 4; ++ni)
    bp[ni] = w1bt + (size_t)(w * 64 + ni * 16 + lr) * IDIM + lk * 8;

  f32x4 acc[4][4];
#pragma unroll
  for (int i = 0; i < 4; ++i)
#pragma unroll
    for (int j = 0; j < 4; ++j) acc[i][j] = f32x4{0.f, 0.f, 0.f, 0.f};
  float sum4[4] = {0.f, 0.f, 0.f, 0.f}, ssq4[4] = {0.f, 0.f, 0.f, 0.f};

  f32x4 A0[4][2], A1[4][2];
  short8 B0[4], B1[4];

  auto issue = [&](int s, f32x4 (&A)[4][2], short8 (&B)[4]) {
#pragma unroll
    for (int mi = 0; mi < 4; ++mi) {
      const f32x4* p = reinterpret_cast<const f32x4*>(ap[mi] + s * 32);
      A[mi][0] = p[0];
      A[mi][1] = p[1];
    }
#pragma unroll
    for (int ni = 0; ni < 4; ++ni)
      B[ni] = *reinterpret_cast<const short8*>(bp[ni] + s * 32);
  };
  auto comp = [&](f32x4 (&A)[4][2], short8 (&B)[4]) {
    short8 av[4];
#pragma unroll
    for (int mi = 0; mi < 4; ++mi) {
      const f32x4 x = A[mi][0], y = A[mi][1];
      sum4[mi] += ((x[0] + x[1]) + (x[2] + x[3])) +
                  ((y[0] + y[1]) + (y[2] + y[3]));
      float q = ssq4[mi];
      q = fmaf(x[0], x[0], q); q = fmaf(x[1], x[1], q);
      q = fmaf(x[2], x[2], q); q = fmaf(x[3], x[3], q);
      q = fmaf(y[0], y[0], q); q = fmaf(y[1], y[1], q);
      q = fmaf(y[2], y[2], q); q = fmaf(y[3], y[3], q);
      ssq4[mi] = q;
      const u32x4 ua = {pk_bf16(x[0], x[1]), pk_bf16(x[2], x[3]),
                        pk_bf16(y[0], y[1]), pk_bf16(y[2], y[3])};
      __builtin_memcpy(&av[mi], &ua, 16);
    }
#pragma unroll
    for (int mi = 0; mi < 4; ++mi)
#pragma unroll
      for (int ni = 0; ni < 4; ++ni)
        acc[mi][ni] = __builtin_amdgcn_mfma_f32_16x16x32_bf16(av[mi], B[ni],
                                                              acc[mi][ni], 0, 0, 0);
  };

  issue(0, A0, B0);
  issue(1, A1, B1);
#pragma unroll 1
  for (int s = 0; s < 32; s += 2) {
    comp(A0, B0);                       // waits (counted) on A0/B0 only
    if (s + 2 < 32) issue(s + 2, A0, B0);
    comp(A1, B1);
    if (s + 3 < 32) issue(s + 3, A1, B1);
  }

  // per-wave row stats (each wave loaded every row in full)
#pragma unroll
  for (int mi = 0; mi < 4; ++mi) {
    float s_ = sum4[mi], q_ = ssq4[mi];
    s_ += __shfl_xor(s_, 16); s_ += __shfl_xor(s_, 32);
    q_ += __shfl_xor(q_, 16); q_ += __shfl_xor(q_, 32);
    if (lk == 0) {
      const float mu  = s_ * (1.f / 1024.f);
      const float var = q_ * (1.f / 1024.f) - mu * mu;
      const float rs  = rsqrtf(var + 1e-5f);
      statsS[w][(mi * 16 + lr) * 2]     = mu * rs;
      statsS[w][(mi * 16 + lr) * 2 + 1] = rs;
    }
  }
  __syncthreads();

  // epilogue: folded-LN affine -> exact GELU -> second GEMM (256 -> 2)
  float po0[16], po1[16];
#pragma unroll
  for (int i = 0; i < 16; ++i) { po0[i] = 0.f; po1[i] = 0.f; }
#pragma unroll
  for (int ni = 0; ni < 4; ++ni) {
    const int n = w * 64 + ni * 16 + lr;
    const float t2n = t2g[n];
    const float tcn = tc1g[n];
    const float w20 = w2g[n * 2];
    const float w21 = w2g[n * 2 + 1];
#pragma unroll
    for (int mi = 0; mi < 4; ++mi) {
#pragma unroll
      for (int j = 0; j < 4; ++j) {
        const int r = mi * 16 + lk * 4 + j;
        const float mrs = statsS[w][r * 2];
        const float rs  = statsS[w][r * 2 + 1];
        const float z  = fmaf(rs, acc[mi][ni][j], fmaf(-mrs, t2n, tcn));
        const float hh = 0.5f * z * (1.f + erff(z * 0.70710678118654752f));
        po0[mi * 4 + j] = fmaf(hh, w20, po0[mi * 4 + j]);
        po1[mi * 4 + j] = fmaf(hh, w21, po1[mi * 4 + j]);
      }
    }
  }
#pragma unroll
  for (int i = 0; i < 16; ++i) {
#pragma unroll
    for (int d = 1; d < 16; d <<= 1) {
      po0[i] += __shfl_xor(po0[i], d);
      po1[i] += __shfl_xor(po1[i], d);
    }
  }
  if (lr == 0) {
#pragma unroll
    for (int mi = 0; mi < 4; ++mi)
#pragma unroll
      for (int j = 0; j < 4; ++j) {
        const int r = mi * 16 + lk * 4 + j;
        poutS[w][r * 2 + 0] = po0[mi * 4 + j];
        poutS[w][r * 2 + 1] = po1[mi * 4 + j];
      }
  }
  __syncthreads();
  if (t < 128) {
    const int r = t >> 1, o = t & 1;
    const float v = poutS[0][r * 2 + o] + poutS[1][r * 2 + o] +
                    poutS[2][r * 2 + o] + poutS[3][r * 2 + o];
    out[(size_t)(m0 + r) * 2 + o] = v + b2g[o];
  }
}

extern "C" void kernel_launch(void* const* d_in, const int* in_sizes, int n_in,
                              void* d_out, int out_size, void* d_ws, size_t ws_size,
                              hipStream_t stream) {
  const float* emb = (const float*)d_in[0];
  const float* lnw = (const float*)d_in[1];
  const float* lnb = (const float*)d_in[2];
  const float* W1  = (const float*)d_in[3];
  const float* b1  = (const float*)d_in[4];
  const float* W2  = (const float*)d_in[5];
  const float* b2  = (const float*)d_in[6];
  float* out = (float*)d_out;

  unsigned short* w1bt = (unsigned short*)d_ws;  // 512 KiB
  float* t2g  = (float*)((char*)d_ws + 524288);
  float* tc1g = (float*)((char*)d_ws + 524288 + 1024);

  prep_kernel<<<64, 256, 0, stream>>>(W1, lnw, lnb, b1, w1bt, t2g, tc1g);
  head_kernel<<<65536 / 64, 256, 0, stream>>>(emb, w1bt, t2g, tc1g, W2, b2, out);
}